// Round 4
// baseline (1026.995 us; speedup 1.0000x reference)
//
#include <hip/hip_runtime.h>
#include <cstdint>

#define B_ 64
#define N_ 512
#define D_ 256
#define L_ 4

typedef __bf16 bf16;
typedef __attribute__((ext_vector_type(8))) __bf16 bf16x8;
typedef __attribute__((ext_vector_type(4))) __bf16 bf16x4;
typedef __attribute__((ext_vector_type(4))) float f32x4;

#define MFMA16(a, b, c) __builtin_amdgcn_mfma_f32_16x16x32_bf16((a), (b), (c), 0, 0, 0)

__device__ __forceinline__ float sigmoidf_(float z) {
  return 1.0f / (1.0f + __expf(-z));
}

// ===========================================================================
// R0-R3 lesson: the fused 10-barrier megakernel convoys — all waves stall
// together regardless of occupancy (R2) or forced ILP (R3); all pipes <12%.
// This version splits each layer into 5 flat kernels (1 barrier each for the
// GEMMs, 3 for attn). Intermediates round-trip through workspace (L2/L3).
// ===========================================================================

// ---------------------------------------------------------------------------
// gemm_nt<RELU>: out[r][c] = act(A[r][:] . W[c][:] + bias[c]) -> bf16
// 64-row M-tiles, 256 threads, wave w -> cols [64w,64w+64). Grid 512.
// ---------------------------------------------------------------------------
template <bool RELU>
__global__ __launch_bounds__(256) void gemm_nt(
    const bf16* __restrict__ A, const bf16* __restrict__ W,
    const float* __restrict__ bias, bf16* __restrict__ out)
{
  __shared__ bf16 as_[64 * 264];
  const int tid = threadIdx.x, w = tid >> 6, lane = tid & 63;
  const int l16 = lane & 15, quad = lane >> 4;
  const int wg = blockIdx.x;
  const int lid = (wg & 7) * 64 + (wg >> 3);   // XCD-batch swizzle (512 wgs)
  const size_t row0 = (size_t)lid * 64;
#pragma unroll
  for (int e = 0; e < 8; ++e) {
    const int cc = tid + e * 256;
    const int r = cc >> 5, cg = cc & 31;
    *(bf16x8*)&as_[r * 264 + cg * 8] =
        *(const bf16x8*)(A + (row0 + r) * D_ + cg * 8);
  }
  __syncthreads();
  f32x4 acc[4][4] = {};
#pragma unroll
  for (int ks = 0; ks < 8; ++ks) {
    bf16x8 af[4];
#pragma unroll
    for (int m = 0; m < 4; ++m)
      af[m] = *(const bf16x8*)&as_[(16 * m + l16) * 264 + ks * 32 + quad * 8];
    bf16x8 bw[4];
#pragma unroll
    for (int i = 0; i < 4; ++i) {
      const int col = 64 * w + 16 * i + l16;
      bw[i] = *(const bf16x8*)(W + (size_t)col * D_ + ks * 32 + quad * 8);
    }
#pragma unroll
    for (int m = 0; m < 4; ++m)
#pragma unroll
      for (int i = 0; i < 4; ++i) acc[m][i] = MFMA16(af[m], bw[i], acc[m][i]);
  }
#pragma unroll
  for (int m = 0; m < 4; ++m)
#pragma unroll
    for (int i = 0; i < 4; ++i) {
      const int col = 64 * w + 16 * i + l16;
      const float bv = bias[col];
#pragma unroll
      for (int r = 0; r < 4; ++r) {
        float t = acc[m][i][r] + bv;
        if (RELU) t = fmaxf(t, 0.0f);
        out[(row0 + 16 * m + quad * 4 + r) * D_ + col] = (bf16)t;
      }
    }
}

// ---------------------------------------------------------------------------
// l1_gemm: x = relu(H@W1^T + b1) + resid(bf16 via xT layout) -> xb_out, xT_out
// ---------------------------------------------------------------------------
__global__ __launch_bounds__(256) void l1_gemm(
    const bf16* __restrict__ H, const bf16* __restrict__ W,
    const float* __restrict__ bias, const bf16* __restrict__ xT_resid,
    bf16* __restrict__ xb_out, bf16* __restrict__ xT_out)
{
  __shared__ bf16 as_[64 * 264];
  const int tid = threadIdx.x, w = tid >> 6, lane = tid & 63;
  const int l16 = lane & 15, quad = lane >> 4;
  const int wg = blockIdx.x;
  const int lid = (wg & 7) * 64 + (wg >> 3);
  const size_t row0 = (size_t)lid * 64;
  const int b = lid >> 3;               // 8 blocks of 64 rows per batch
  const int n0 = (lid & 7) * 64;
#pragma unroll
  for (int e = 0; e < 8; ++e) {
    const int cc = tid + e * 256;
    const int r = cc >> 5, cg = cc & 31;
    *(bf16x8*)&as_[r * 264 + cg * 8] =
        *(const bf16x8*)(H + (row0 + r) * D_ + cg * 8);
  }
  __syncthreads();
  f32x4 acc[4][4] = {};
#pragma unroll
  for (int ks = 0; ks < 8; ++ks) {
    bf16x8 af[4];
#pragma unroll
    for (int m = 0; m < 4; ++m)
      af[m] = *(const bf16x8*)&as_[(16 * m + l16) * 264 + ks * 32 + quad * 8];
    bf16x8 bw[4];
#pragma unroll
    for (int i = 0; i < 4; ++i) {
      const int col = 64 * w + 16 * i + l16;
      bw[i] = *(const bf16x8*)(W + (size_t)col * D_ + ks * 32 + quad * 8);
    }
#pragma unroll
    for (int m = 0; m < 4; ++m)
#pragma unroll
      for (int i = 0; i < 4; ++i) acc[m][i] = MFMA16(af[m], bw[i], acc[m][i]);
  }
#pragma unroll
  for (int m = 0; m < 4; ++m)
#pragma unroll
    for (int i = 0; i < 4; ++i) {
      const int d = 64 * w + 16 * i + l16;
      const float bv = bias[d];
      const int nloc = n0 + 16 * m + quad * 4;
      const bf16x4 x0v = *(const bf16x4*)&xT_resid[((size_t)(b * D_ + d)) * N_ + nloc];
      bf16x4 tv;
#pragma unroll
      for (int r = 0; r < 4; ++r) {
        const float t = fmaxf(acc[m][i][r] + bv, 0.0f) + (float)x0v[r];
        const bf16 tb = (bf16)t;
        xb_out[(row0 + 16 * m + quad * 4 + r) * D_ + d] = tb;
        tv[r] = tb;
      }
      *(bf16x4*)&xT_out[((size_t)(b * D_ + d)) * N_ + nloc] = tv;
    }
}

// ---------------------------------------------------------------------------
// pv_gemm: x' = Pn @ x, A = normalized P read from attls f32, cvt->bf16 in
// LDS; B = xT streamed. 64-row tiles, grid 512. LDS 66.6KB -> 2 blocks/CU.
// ---------------------------------------------------------------------------
__global__ __launch_bounds__(256) void pv_gemm(
    const float* __restrict__ Pn, const bf16* __restrict__ xT,
    bf16* __restrict__ out)
{
  __shared__ bf16 as_[64 * 520];
  const int tid = threadIdx.x, w = tid >> 6, lane = tid & 63;
  const int l16 = lane & 15, quad = lane >> 4;
  const int wg = blockIdx.x;
  const int lid = (wg & 7) * 64 + (wg >> 3);
  const int b = lid >> 3;
  const int n0 = (lid & 7) * 64;
  const size_t pbase = ((size_t)b * N_ + n0) * N_;
#pragma unroll
  for (int e = 0; e < 32; ++e) {
    const int idx = tid + e * 256;
    const int row = idx >> 7, c4 = (idx & 127) * 4;
    const float4 v = *(const float4*)(Pn + pbase + (size_t)row * N_ + c4);
    bf16x4 o;
    o[0] = (bf16)v.x; o[1] = (bf16)v.y; o[2] = (bf16)v.z; o[3] = (bf16)v.w;
    *(bf16x4*)&as_[row * 520 + c4] = o;
  }
  __syncthreads();
  f32x4 acc[4][4] = {};
  const bf16* xTB = xT + (size_t)b * D_ * N_;
#pragma unroll
  for (int ks = 0; ks < 16; ++ks) {
    bf16x8 af[4];
#pragma unroll
    for (int m = 0; m < 4; ++m)
      af[m] = *(const bf16x8*)&as_[(16 * m + l16) * 520 + ks * 32 + quad * 8];
    bf16x8 bt[4];
#pragma unroll
    for (int i = 0; i < 4; ++i) {
      const int d = 64 * w + 16 * i + l16;
      bt[i] = *(const bf16x8*)(xTB + (size_t)d * N_ + ks * 32 + quad * 8);
    }
#pragma unroll
    for (int m = 0; m < 4; ++m)
#pragma unroll
      for (int i = 0; i < 4; ++i) acc[m][i] = MFMA16(af[m], bt[i], acc[m][i]);
  }
#pragma unroll
  for (int m = 0; m < 4; ++m)
#pragma unroll
    for (int i = 0; i < 4; ++i) {
      const int d = 64 * w + 16 * i + l16;
#pragma unroll
      for (int r = 0; r < 4; ++r)
        out[((size_t)(b * N_ + n0 + 16 * m + quad * 4 + r)) * D_ + d] = (bf16)acc[m][i][r];
    }
}

// ---------------------------------------------------------------------------
// attn_kernel: P = sigmoid(q @ xb^T) masked; rowsum; normalize; write attls.
// 32-row strips, grid 1024. q fragments hoisted from global. 3 barriers.
// ---------------------------------------------------------------------------
__global__ __launch_bounds__(256) void attn_kernel(
    const bf16* __restrict__ qg, const bf16* __restrict__ xb_in,
    const float* __restrict__ adj, const unsigned short* __restrict__ bits_in,
    unsigned short* __restrict__ bits_out, float* __restrict__ outA)
{
  __shared__ bf16 xps[32 * 520];
  __shared__ float psum[4][32];
  __shared__ float rinvs[32];
  __shared__ unsigned int bits_s[512];

  const int tid = threadIdx.x, w = tid >> 6, lane = tid & 63;
  const int l16 = lane & 15, quad = lane >> 4;
  const int wg = blockIdx.x;
  const int lid = (wg & 7) * 128 + (wg >> 3);
  const int b = lid >> 4;
  const int row0 = (lid & 15) * 32;

  if (bits_in) {
#pragma unroll
    for (int e = 0; e < 2; ++e) {
      const int t = tid + e * 256;
      bits_s[t] = ((const unsigned int*)bits_in)[((size_t)b * N_ + row0) * 16 + t];
    }
  }
  // hoist q fragments for this strip (reused across all 4 column-blocks)
  bf16x8 afc[8][2];
#pragma unroll
  for (int ks = 0; ks < 8; ++ks)
#pragma unroll
    for (int m = 0; m < 2; ++m)
      afc[ks][m] = *(const bf16x8*)(qg +
          ((size_t)(b * N_ + row0 + 16 * m + l16)) * D_ + ks * 32 + quad * 8);
  __syncthreads();   // bits_s visible

  float p[2][4] = {};
  const bf16* xbB = xb_in + (size_t)b * N_ * D_;
  for (int ct = 0; ct < 4; ++ct) {
    f32x4 acc1[2][2] = {};
#pragma unroll
    for (int ks = 0; ks < 8; ++ks) {
      bf16x8 bx[2];
#pragma unroll
      for (int jt = 0; jt < 2; ++jt) {
        const int gcol = ct * 128 + w * 32 + jt * 16 + l16;
        bx[jt] = *(const bf16x8*)(xbB + (size_t)gcol * D_ + ks * 32 + quad * 8);
      }
#pragma unroll
      for (int m = 0; m < 2; ++m)
#pragma unroll
        for (int jt = 0; jt < 2; ++jt)
          acc1[m][jt] = MFMA16(afc[ks][m], bx[jt], acc1[m][jt]);
    }
#pragma unroll
    for (int jt = 0; jt < 2; ++jt) {
      const int lcol = ct * 128 + w * 32 + jt * 16 + l16;
      const int piece = ct * 8 + w * 2 + jt;
#pragma unroll
      for (int m = 0; m < 2; ++m)
#pragma unroll
        for (int r = 0; r < 4; ++r) {
          const int row = 16 * m + quad * 4 + r;
          const int grow = row0 + row;
          float av;
          if (bits_in) {
            const unsigned short m16 = ((const unsigned short*)bits_s)[row * 32 + piece];
            av = (float)((m16 >> l16) & 1);
          } else {
            av = __builtin_nontemporal_load(
                adj + ((size_t)b * N_ + grow) * N_ + lcol);
          }
          const bool diag = (grow == lcol);
          if (bits_out) {
            const unsigned long long bal = __ballot(diag || av != 0.0f);
            if (l16 == 0)
              bits_out[((size_t)b * N_ + row0 + 16 * m + 4 * quad + r) * 32 + piece] =
                  (unsigned short)((bal >> (quad * 16)) & 0xFFFFull);
          }
          const float sg = sigmoidf_(acc1[m][jt][r]);
          const float v = diag ? (sg + 1e-5f) : sg * av;
          const bf16 bv = (bf16)v;
          xps[row * 520 + lcol] = bv;
          p[m][r] += (float)bv;
        }
    }
  }
#pragma unroll
  for (int m = 0; m < 2; ++m)
#pragma unroll
    for (int r = 0; r < 4; ++r) {
#pragma unroll
      for (int msk = 1; msk < 16; msk <<= 1) p[m][r] += __shfl_xor(p[m][r], msk, 64);
    }
  if (l16 == 0) {
#pragma unroll
    for (int m = 0; m < 2; ++m)
#pragma unroll
      for (int r = 0; r < 4; ++r) psum[w][16 * m + quad * 4 + r] = p[m][r];
  }
  __syncthreads();
  if (tid < 32)
    rinvs[tid] = 1.0f / (psum[0][tid] + psum[1][tid] + psum[2][tid] + psum[3][tid]);
  __syncthreads();

  const size_t abase = ((size_t)b * N_ + row0) * N_;
#pragma unroll
  for (int e = 0; e < 16; ++e) {
    const int idx = tid + e * 256;
    const int row = idx >> 7, c4 = (idx & 127) * 4;
    const float ri = rinvs[row];
    bf16x4 pv = *(const bf16x4*)&xps[row * 520 + c4];
    f32x4 nv;
    nv[0] = (float)pv[0] * ri; nv[1] = (float)pv[1] * ri;
    nv[2] = (float)pv[2] * ri; nv[3] = (float)pv[3] * ri;
    *(f32x4*)(outA + abase + (size_t)row * N_ + c4) = nv;  // L2/L3-resident: pv reads it next
  }
}

// ---------------------------------------------------------------------------
// final_proj: out = x @ Wf^T + bf (f32), per 32-row strip.
// ---------------------------------------------------------------------------
__global__ __launch_bounds__(256, 4) void final_proj(
    const bf16* __restrict__ xin, const bf16* __restrict__ Wf,
    const float* __restrict__ bfv, float* __restrict__ outX)
{
  __shared__ bf16 as_[32 * 264];
  const int tid = threadIdx.x, w = tid >> 6, lane = tid & 63;
  const int l16 = lane & 15, quad = lane >> 4;
  const int wg = blockIdx.x;
  const int lid = (wg & 7) * 128 + (wg >> 3);
  const int row0g = lid * 32;
#pragma unroll
  for (int e = 0; e < 4; ++e) {
    const int cc = tid + e * 256;
    const int r = cc >> 5, cg = cc & 31;
    *(bf16x8*)&as_[r * 264 + cg * 8] =
        *(const bf16x8*)(xin + ((size_t)(row0g + r)) * D_ + cg * 8);
  }
  __syncthreads();
  f32x4 acc[2][4] = {};
#pragma unroll
  for (int ks = 0; ks < 8; ++ks) {
    bf16x8 af[2];
#pragma unroll
    for (int m = 0; m < 2; ++m)
      af[m] = *(const bf16x8*)&as_[(16 * m + l16) * 264 + ks * 32 + quad * 8];
    bf16x8 bw[4];
#pragma unroll
    for (int i = 0; i < 4; ++i) {
      const int col = 64 * w + 16 * i + l16;
      bw[i] = *(const bf16x8*)(Wf + (size_t)col * D_ + ks * 32 + quad * 8);
    }
#pragma unroll
    for (int m = 0; m < 2; ++m)
#pragma unroll
      for (int i = 0; i < 4; ++i) acc[m][i] = MFMA16(af[m], bw[i], acc[m][i]);
  }
#pragma unroll
  for (int m = 0; m < 2; ++m)
#pragma unroll
    for (int i = 0; i < 4; ++i) {
      const int col = 64 * w + 16 * i + l16;
      const float bv = bfv[col];
#pragma unroll
      for (int r = 0; r < 4; ++r) {
        const size_t R = (size_t)row0g + 16 * m + quad * 4 + r;
        __builtin_nontemporal_store(acc[m][i][r] + bv, outX + R * D_ + col);
      }
    }
}

// ---------------------------------------------------------------------------
// init: x -> xb bf16, xT bf16 (LDS 32x32 transpose), batch-contiguous XCD map.
// ---------------------------------------------------------------------------
__global__ __launch_bounds__(256) void init_x(
    const float* __restrict__ x, bf16* __restrict__ xb, bf16* __restrict__ xT)
{
  __shared__ float t[32 * 33];
  const int tid = threadIdx.x;
  const int wg = blockIdx.x;                 // 0..8191
  const int lid = (wg & 7) * 1024 + (wg >> 3);
  const int b = lid >> 7, rem = lid & 127;
  const int dt = rem >> 4, nt = rem & 15;
#pragma unroll
  for (int e = 0; e < 4; ++e) {
    const int idx = tid + e * 256;
    const int r = idx >> 5, c = idx & 31;
    const size_t g = ((size_t)(b * N_ + nt * 32 + r)) * D_ + dt * 32 + c;
    const float v = x[g];
    xb[g] = (bf16)v;
    t[r * 33 + c] = v;
  }
  __syncthreads();
#pragma unroll
  for (int e = 0; e < 4; ++e) {
    const int idx = tid + e * 256;
    const int r = idx >> 5, c = idx & 31;
    xT[((size_t)(b * D_ + dt * 32 + r)) * N_ + nt * 32 + c] = (bf16)t[c * 33 + r];
  }
}

__global__ __launch_bounds__(256) void cvt_bf16(
    const float* __restrict__ src, bf16* __restrict__ dst, int n4)
{
  const int i = blockIdx.x * 256 + threadIdx.x;
  if (i < n4) {
    const float4 v = ((const float4*)src)[i];
    bf16x4 o;
    o[0] = (bf16)v.x; o[1] = (bf16)v.y; o[2] = (bf16)v.z; o[3] = (bf16)v.w;
    ((bf16x4*)dst)[i] = o;
  }
}

extern "C" void kernel_launch(void* const* d_in, const int* in_sizes, int n_in,
                              void* d_out, int out_size, void* d_ws, size_t ws_size,
                              hipStream_t stream)
{
  const float* x_in  = (const float*)d_in[0];
  const float* adj   = (const float*)d_in[1];
  const float* wattn = (const float*)d_in[2];
  const float* battn = (const float*)d_in[3];
  const float* w0    = (const float*)d_in[4];
  const float* b0    = (const float*)d_in[5];
  const float* w1    = (const float*)d_in[6];
  const float* b1    = (const float*)d_in[7];
  const float* wf    = (const float*)d_in[8];
  const float* bfin  = (const float*)d_in[9];

  float* out_x    = (float*)d_out;                     // [B,N,D] f32 (final only)
  float* out_attn = out_x + (size_t)B_ * N_ * D_;      // [L,B,N,N]

  const size_t XBN = (size_t)B_ * N_ * D_;
  bf16* wb  = (bf16*)d_ws;                             // 13 * D*D weights
  bf16* xb0 = wb + 13 * (D_ * D_);
  bf16* xT0 = xb0 + XBN;
  bf16* xb1 = xT0 + XBN;
  bf16* xT1 = xb1 + XBN;
  unsigned short* bits = (unsigned short*)(xT1 + XBN); // [B,N,32] uint16
  bf16* q_ws = (bf16*)(bits + (size_t)B_ * N_ * 32);   // q / h (aliased)

  const int DD2 = D_ * D_;
  const int Mfull = B_ * N_;  // 32768

  cvt_bf16<<<dim3((L_ * DD2 / 4 + 255) / 256), 256, 0, stream>>>(wattn, wb, L_ * DD2 / 4);
  cvt_bf16<<<dim3((L_ * DD2 / 4 + 255) / 256), 256, 0, stream>>>(w0, wb + 4 * DD2, L_ * DD2 / 4);
  cvt_bf16<<<dim3((L_ * DD2 / 4 + 255) / 256), 256, 0, stream>>>(w1, wb + 8 * DD2, L_ * DD2 / 4);
  cvt_bf16<<<dim3((DD2 / 4 + 255) / 256), 256, 0, stream>>>(wf, wb + 12 * DD2, DD2 / 4);

  init_x<<<dim3((N_ / 32) * (D_ / 32) * B_), 256, 0, stream>>>(x_in, xb0, xT0);

  bf16* xbs[2] = {xb0, xb1};
  bf16* xTs[2] = {xT0, xT1};
  for (int l = 0; l < L_; ++l) {
    const int pi = l & 1, po = 1 - pi;
    float* outA_l = out_attn + (size_t)l * B_ * N_ * N_;
    // q = x @ Wa^T + ba
    gemm_nt<false><<<dim3(Mfull / 64), 256, 0, stream>>>(
        xbs[pi], wb + l * DD2, battn + l * D_, q_ws);
    // P = sigmoid(q xb^T) masked, normalized -> attls
    attn_kernel<<<dim3((N_ / 32) * B_), 256, 0, stream>>>(
        q_ws, xbs[pi], adj, (l == 0) ? nullptr : bits, (l == 0) ? bits : nullptr,
        outA_l);
    // x' = P @ x  (x' parked in xb_out buffer; overwritten by l1 below)
    pv_gemm<<<dim3(Mfull / 64), 256, 0, stream>>>(outA_l, xTs[pi], xbs[po]);
    // h = relu(x' @ W0^T + b0)  (h parked in q_ws; q dead)
    gemm_nt<true><<<dim3(Mfull / 64), 256, 0, stream>>>(
        xbs[po], wb + (4 + l) * DD2, b0 + l * D_, q_ws);
    // x = relu(h @ W1^T + b1) + x0 -> xb_out, xT_out
    l1_gemm<<<dim3(Mfull / 64), 256, 0, stream>>>(
        q_ws, wb + (8 + l) * DD2, b1 + l * D_, xTs[pi], xbs[po], xTs[po]);
  }
  final_proj<<<dim3(Mfull / 32), 256, 0, stream>>>(xbs[0], wb + 12 * DD2, bfin, out_x);
}

// Round 5
// 959.526 us; speedup vs baseline: 1.0703x; 1.0703x over previous
//
#include <hip/hip_runtime.h>
#include <cstdint>

#define B_ 64
#define N_ 512
#define D_ 256
#define L_ 4

typedef __bf16 bf16;
typedef __attribute__((ext_vector_type(8))) __bf16 bf16x8;
typedef __attribute__((ext_vector_type(4))) __bf16 bf16x4;
typedef __attribute__((ext_vector_type(4))) float f32x4;

#define MFMA16(a, b, c) __builtin_amdgcn_mfma_f32_16x16x32_bf16((a), (b), (c), 0, 0, 0)

__device__ __forceinline__ float sigmoidf_(float z) {
  return 1.0f / (1.0f + __expf(-z));
}

// ===========================================================================
// R0-R4 lesson: all pipes idle, invariant ~230us/layer under occupancy/ILP/
// split changes; fill kernels prove HBM+clocks healthy (6.5 TB/s). Diagnosis:
// per-lane ROW-SCATTERED B-fragment loads (16 cache lines per instruction,
// ~240/thread) saturate the per-CU L1/TA request path + MSHRs -> every wave
// serializes at latency. Fix: FRAGMENT-MAJOR PACKED B-operands: each
// (16-col-tile, 32-K-chunk) fragment stored as 64 lanes x 16B contiguous
// (1KB unit) -> every B-load is one dense 1KB burst.
// Packed unit layout: unit u = r16*KCS + kc ; within unit, lane L holds
// elements src[col = r16*16 + (L&15)][k = kc*32 + (L>>4)*8 + e], e=0..7.
// This is exactly the MFMA B-fragment the kernels consumed before.
// ===========================================================================

// ---------------------------------------------------------------------------
// pack_w: f32 row-major [nmat][256][256] -> packed bf16 fragments.
// 128 units/matrix (r16<16, kc<8), 4 units/block.
// ---------------------------------------------------------------------------
__global__ __launch_bounds__(256) void pack_w(
    const float* __restrict__ src, bf16* __restrict__ dst)
{
  const int tid = threadIdx.x, lane = tid & 63;
  const int U = blockIdx.x * 4 + (tid >> 6);     // global unit
  const int m = U >> 7, u = U & 127;
  const int r16 = u >> 3, kc = u & 7;
  const int row = r16 * 16 + (lane & 15);
  const int k0 = kc * 32 + (lane >> 4) * 8;
  const float* s = src + (size_t)m * D_ * D_ + (size_t)row * D_ + k0;
  const float4 v0 = *(const float4*)s;
  const float4 v1 = *(const float4*)(s + 4);
  bf16x8 o;
  o[0] = (bf16)v0.x; o[1] = (bf16)v0.y; o[2] = (bf16)v0.z; o[3] = (bf16)v0.w;
  o[4] = (bf16)v1.x; o[5] = (bf16)v1.y; o[6] = (bf16)v1.z; o[7] = (bf16)v1.w;
  ((bf16x8*)dst)[(size_t)U * 64 + lane] = o;
}

// ---------------------------------------------------------------------------
// pack_bf: bf16 row-major [64 batches][NR][NC] -> packed fragments.
// 256 units/batch; kcs = NC/32 (8 for xb[512][256], 16 for xT[256][512]).
// ---------------------------------------------------------------------------
__global__ __launch_bounds__(256) void pack_bf(
    const bf16* __restrict__ src, bf16* __restrict__ dst,
    int NC, int kc_shift, int kc_mask)
{
  const int tid = threadIdx.x, lane = tid & 63;
  const int U = blockIdx.x * 4 + (tid >> 6);     // global unit (0..16383)
  const int b = U >> 8, u = U & 255;
  const int r16 = u >> kc_shift, kc = u & kc_mask;
  const int row = r16 * 16 + (lane & 15);
  const int k0 = kc * 32 + (lane >> 4) * 8;
  const bf16x8 v = *(const bf16x8*)(src + (size_t)b * N_ * D_ + (size_t)row * NC + k0);
  ((bf16x8*)dst)[(size_t)U * 64 + lane] = v;
}

// ---------------------------------------------------------------------------
// gemm_nt<RELU>: out = act(A @ W^T + bias) -> bf16. A row-major staged via
// LDS; W packed fragments (KCS=8). 64-row tiles, grid 512.
// ---------------------------------------------------------------------------
template <bool RELU>
__global__ __launch_bounds__(256, 3) void gemm_nt(
    const bf16* __restrict__ A, const bf16* __restrict__ Wpk,
    const float* __restrict__ bias, bf16* __restrict__ out)
{
  __shared__ bf16 as_[64 * 264];
  const int tid = threadIdx.x, w = tid >> 6, lane = tid & 63;
  const int l16 = lane & 15, quad = lane >> 4;
  const int wg = blockIdx.x;
  const int lid = (wg & 7) * 64 + (wg >> 3);
  const size_t row0 = (size_t)lid * 64;
#pragma unroll
  for (int e = 0; e < 8; ++e) {
    const int cc = tid + e * 256;
    const int r = cc >> 5, cg = cc & 31;
    *(bf16x8*)&as_[r * 264 + cg * 8] =
        *(const bf16x8*)(A + (row0 + r) * D_ + cg * 8);
  }
  __syncthreads();
  const bf16x8* Wp = (const bf16x8*)Wpk;
  f32x4 acc[4][4] = {};
#pragma unroll
  for (int ks = 0; ks < 8; ++ks) {
    bf16x8 af[4];
#pragma unroll
    for (int m = 0; m < 4; ++m)
      af[m] = *(const bf16x8*)&as_[(16 * m + l16) * 264 + ks * 32 + quad * 8];
    bf16x8 bw[4];
#pragma unroll
    for (int i = 0; i < 4; ++i)
      bw[i] = Wp[((size_t)((4 * w + i) * 8 + ks)) * 64 + lane];  // dense 1KB
#pragma unroll
    for (int m = 0; m < 4; ++m)
#pragma unroll
      for (int i = 0; i < 4; ++i) acc[m][i] = MFMA16(af[m], bw[i], acc[m][i]);
  }
#pragma unroll
  for (int m = 0; m < 4; ++m)
#pragma unroll
    for (int i = 0; i < 4; ++i) {
      const int col = 64 * w + 16 * i + l16;
      const float bv = bias[col];
#pragma unroll
      for (int r = 0; r < 4; ++r) {
        float t = acc[m][i][r] + bv;
        if (RELU) t = fmaxf(t, 0.0f);
        out[(row0 + 16 * m + quad * 4 + r) * D_ + col] = (bf16)t;
      }
    }
}

// ---------------------------------------------------------------------------
// l1_gemm: x = relu(H@W1^T + b1) + resid -> xb_out, xT_out. W1 packed.
// ---------------------------------------------------------------------------
__global__ __launch_bounds__(256, 3) void l1_gemm(
    const bf16* __restrict__ H, const bf16* __restrict__ Wpk,
    const float* __restrict__ bias, const bf16* __restrict__ xT_resid,
    bf16* __restrict__ xb_out, bf16* __restrict__ xT_out)
{
  __shared__ bf16 as_[64 * 264];
  const int tid = threadIdx.x, w = tid >> 6, lane = tid & 63;
  const int l16 = lane & 15, quad = lane >> 4;
  const int wg = blockIdx.x;
  const int lid = (wg & 7) * 64 + (wg >> 3);
  const size_t row0 = (size_t)lid * 64;
  const int b = lid >> 3;
  const int n0 = (lid & 7) * 64;
#pragma unroll
  for (int e = 0; e < 8; ++e) {
    const int cc = tid + e * 256;
    const int r = cc >> 5, cg = cc & 31;
    *(bf16x8*)&as_[r * 264 + cg * 8] =
        *(const bf16x8*)(H + (row0 + r) * D_ + cg * 8);
  }
  __syncthreads();
  const bf16x8* Wp = (const bf16x8*)Wpk;
  f32x4 acc[4][4] = {};
#pragma unroll
  for (int ks = 0; ks < 8; ++ks) {
    bf16x8 af[4];
#pragma unroll
    for (int m = 0; m < 4; ++m)
      af[m] = *(const bf16x8*)&as_[(16 * m + l16) * 264 + ks * 32 + quad * 8];
    bf16x8 bw[4];
#pragma unroll
    for (int i = 0; i < 4; ++i)
      bw[i] = Wp[((size_t)((4 * w + i) * 8 + ks)) * 64 + lane];
#pragma unroll
    for (int m = 0; m < 4; ++m)
#pragma unroll
      for (int i = 0; i < 4; ++i) acc[m][i] = MFMA16(af[m], bw[i], acc[m][i]);
  }
#pragma unroll
  for (int m = 0; m < 4; ++m)
#pragma unroll
    for (int i = 0; i < 4; ++i) {
      const int d = 64 * w + 16 * i + l16;
      const float bv = bias[d];
      const int nloc = n0 + 16 * m + quad * 4;
      const bf16x4 x0v = *(const bf16x4*)&xT_resid[((size_t)(b * D_ + d)) * N_ + nloc];
      bf16x4 tv;
#pragma unroll
      for (int r = 0; r < 4; ++r) {
        const float t = fmaxf(acc[m][i][r] + bv, 0.0f) + (float)x0v[r];
        const bf16 tb = (bf16)t;
        xb_out[(row0 + 16 * m + quad * 4 + r) * D_ + d] = tb;
        tv[r] = tb;
      }
      *(bf16x4*)&xT_out[((size_t)(b * D_ + d)) * N_ + nloc] = tv;
    }
}

// ---------------------------------------------------------------------------
// pv_gemm: x' = Pn @ x. A = attls f32 staged->bf16 in LDS (coalesced);
// B = xT packed fragments (KCS=16). 64-row tiles, grid 512, 2 blocks/CU.
// ---------------------------------------------------------------------------
__global__ __launch_bounds__(256, 2) void pv_gemm(
    const float* __restrict__ Pn, const bf16* __restrict__ xTpk,
    bf16* __restrict__ out)
{
  __shared__ bf16 as_[64 * 520];
  const int tid = threadIdx.x, w = tid >> 6, lane = tid & 63;
  const int l16 = lane & 15, quad = lane >> 4;
  const int wg = blockIdx.x;
  const int lid = (wg & 7) * 64 + (wg >> 3);
  const int b = lid >> 3;
  const int n0 = (lid & 7) * 64;
  const size_t pbase = ((size_t)b * N_ + n0) * N_;
#pragma unroll
  for (int e = 0; e < 32; ++e) {
    const int idx = tid + e * 256;
    const int row = idx >> 7, c4 = (idx & 127) * 4;
    const float4 v = *(const float4*)(Pn + pbase + (size_t)row * N_ + c4);
    bf16x4 o;
    o[0] = (bf16)v.x; o[1] = (bf16)v.y; o[2] = (bf16)v.z; o[3] = (bf16)v.w;
    *(bf16x4*)&as_[row * 520 + c4] = o;
  }
  __syncthreads();
  const bf16x8* Xp = (const bf16x8*)xTpk + (size_t)b * 16384;  // 256 units/batch
  f32x4 acc[4][4] = {};
#pragma unroll
  for (int ks = 0; ks < 16; ++ks) {
    bf16x8 af[4];
#pragma unroll
    for (int m = 0; m < 4; ++m)
      af[m] = *(const bf16x8*)&as_[(16 * m + l16) * 520 + ks * 32 + quad * 8];
    bf16x8 bt[4];
#pragma unroll
    for (int i = 0; i < 4; ++i)
      bt[i] = Xp[((size_t)((4 * w + i) * 16 + ks)) * 64 + lane];  // dense 1KB
#pragma unroll
    for (int m = 0; m < 4; ++m)
#pragma unroll
      for (int i = 0; i < 4; ++i) acc[m][i] = MFMA16(af[m], bt[i], acc[m][i]);
  }
#pragma unroll
  for (int m = 0; m < 4; ++m)
#pragma unroll
    for (int i = 0; i < 4; ++i) {
      const int d = 64 * w + 16 * i + l16;
#pragma unroll
      for (int r = 0; r < 4; ++r)
        out[((size_t)(b * N_ + n0 + 16 * m + quad * 4 + r)) * D_ + d] = (bf16)acc[m][i][r];
    }
}

// ---------------------------------------------------------------------------
// attn_kernel: P = sigmoid(q @ x^T) masked; rowsum; normalize -> attls.
// A = q staged via LDS (coalesced); B = xb packed fragments (KCS=8).
// 32-row strips, grid 1024, 3 blocks/CU.
// ---------------------------------------------------------------------------
__global__ __launch_bounds__(256, 3) void attn_kernel(
    const bf16* __restrict__ qg, const bf16* __restrict__ xbpk,
    const float* __restrict__ adj, const unsigned short* __restrict__ bits_in,
    unsigned short* __restrict__ bits_out, float* __restrict__ outA)
{
  __shared__ bf16 q_s[32 * 264];
  __shared__ bf16 xps[32 * 520];
  __shared__ float psum[4][32];
  __shared__ float rinvs[32];
  __shared__ unsigned int bits_s[512];

  const int tid = threadIdx.x, w = tid >> 6, lane = tid & 63;
  const int l16 = lane & 15, quad = lane >> 4;
  const int wg = blockIdx.x;
  const int lid = (wg & 7) * 128 + (wg >> 3);
  const int b = lid >> 4;
  const int row0 = (lid & 15) * 32;

  // coalesced q strip staging
#pragma unroll
  for (int e = 0; e < 4; ++e) {
    const int cc = tid + e * 256;
    const int r = cc >> 5, cg = cc & 31;
    *(bf16x8*)&q_s[r * 264 + cg * 8] =
        *(const bf16x8*)(qg + ((size_t)(b * N_ + row0 + r)) * D_ + cg * 8);
  }
  if (bits_in) {
#pragma unroll
    for (int e = 0; e < 2; ++e) {
      const int t = tid + e * 256;
      bits_s[t] = ((const unsigned int*)bits_in)[((size_t)b * N_ + row0) * 16 + t];
    }
  }
  __syncthreads();

  bf16x8 afc[8][2];
#pragma unroll
  for (int ks = 0; ks < 8; ++ks)
#pragma unroll
    for (int m = 0; m < 2; ++m)
      afc[ks][m] = *(const bf16x8*)&q_s[(16 * m + l16) * 264 + ks * 32 + quad * 8];

  float p[2][4] = {};
  const bf16x8* Xp = (const bf16x8*)xbpk + (size_t)b * 16384;  // 256 units/batch
  for (int ct = 0; ct < 4; ++ct) {
    f32x4 acc1[2][2] = {};
#pragma unroll
    for (int ks = 0; ks < 8; ++ks) {
      bf16x8 bx[2];
#pragma unroll
      for (int jt = 0; jt < 2; ++jt)
        bx[jt] = Xp[((size_t)((ct * 8 + w * 2 + jt) * 8 + ks)) * 64 + lane];  // dense
#pragma unroll
      for (int m = 0; m < 2; ++m)
#pragma unroll
        for (int jt = 0; jt < 2; ++jt)
          acc1[m][jt] = MFMA16(afc[ks][m], bx[jt], acc1[m][jt]);
    }
#pragma unroll
    for (int jt = 0; jt < 2; ++jt) {
      const int lcol = ct * 128 + w * 32 + jt * 16 + l16;
      const int piece = ct * 8 + w * 2 + jt;
#pragma unroll
      for (int m = 0; m < 2; ++m)
#pragma unroll
        for (int r = 0; r < 4; ++r) {
          const int row = 16 * m + quad * 4 + r;
          const int grow = row0 + row;
          float av;
          if (bits_in) {
            const unsigned short m16 = ((const unsigned short*)bits_s)[row * 32 + piece];
            av = (float)((m16 >> l16) & 1);
          } else {
            av = __builtin_nontemporal_load(
                adj + ((size_t)b * N_ + grow) * N_ + lcol);
          }
          const bool diag = (grow == lcol);
          if (bits_out) {
            const unsigned long long bal = __ballot(diag || av != 0.0f);
            if (l16 == 0)
              bits_out[((size_t)b * N_ + row0 + 16 * m + 4 * quad + r) * 32 + piece] =
                  (unsigned short)((bal >> (quad * 16)) & 0xFFFFull);
          }
          const float sg = sigmoidf_(acc1[m][jt][r]);
          const float v = diag ? (sg + 1e-5f) : sg * av;
          const bf16 bv = (bf16)v;
          xps[row * 520 + lcol] = bv;
          p[m][r] += (float)bv;
        }
    }
  }
#pragma unroll
  for (int m = 0; m < 2; ++m)
#pragma unroll
    for (int r = 0; r < 4; ++r) {
#pragma unroll
      for (int msk = 1; msk < 16; msk <<= 1) p[m][r] += __shfl_xor(p[m][r], msk, 64);
    }
  if (l16 == 0) {
#pragma unroll
    for (int m = 0; m < 2; ++m)
#pragma unroll
      for (int r = 0; r < 4; ++r) psum[w][16 * m + quad * 4 + r] = p[m][r];
  }
  __syncthreads();
  if (tid < 32)
    rinvs[tid] = 1.0f / (psum[0][tid] + psum[1][tid] + psum[2][tid] + psum[3][tid]);
  __syncthreads();

  const size_t abase = ((size_t)b * N_ + row0) * N_;
#pragma unroll
  for (int e = 0; e < 16; ++e) {
    const int idx = tid + e * 256;
    const int row = idx >> 7, c4 = (idx & 127) * 4;
    const float ri = rinvs[row];
    bf16x4 pv = *(const bf16x4*)&xps[row * 520 + c4];
    f32x4 nv;
    nv[0] = (float)pv[0] * ri; nv[1] = (float)pv[1] * ri;
    nv[2] = (float)pv[2] * ri; nv[3] = (float)pv[3] * ri;
    *(f32x4*)(outA + abase + (size_t)row * N_ + c4) = nv;
  }
}

// ---------------------------------------------------------------------------
// final_proj: out = x @ Wf^T + bf (f32). Wf packed. 32-row strips.
// ---------------------------------------------------------------------------
__global__ __launch_bounds__(256, 4) void final_proj(
    const bf16* __restrict__ xin, const bf16* __restrict__ Wpk,
    const float* __restrict__ bfv, float* __restrict__ outX)
{
  __shared__ bf16 as_[32 * 264];
  const int tid = threadIdx.x, w = tid >> 6, lane = tid & 63;
  const int l16 = lane & 15, quad = lane >> 4;
  const int wg = blockIdx.x;
  const int lid = (wg & 7) * 128 + (wg >> 3);
  const int row0g = lid * 32;
#pragma unroll
  for (int e = 0; e < 4; ++e) {
    const int cc = tid + e * 256;
    const int r = cc >> 5, cg = cc & 31;
    *(bf16x8*)&as_[r * 264 + cg * 8] =
        *(const bf16x8*)(xin + ((size_t)(row0g + r)) * D_ + cg * 8);
  }
  __syncthreads();
  const bf16x8* Wp = (const bf16x8*)Wpk;
  f32x4 acc[2][4] = {};
#pragma unroll
  for (int ks = 0; ks < 8; ++ks) {
    bf16x8 af[2];
#pragma unroll
    for (int m = 0; m < 2; ++m)
      af[m] = *(const bf16x8*)&as_[(16 * m + l16) * 264 + ks * 32 + quad * 8];
    bf16x8 bw[4];
#pragma unroll
    for (int i = 0; i < 4; ++i)
      bw[i] = Wp[((size_t)((4 * w + i) * 8 + ks)) * 64 + lane];
#pragma unroll
    for (int m = 0; m < 2; ++m)
#pragma unroll
      for (int i = 0; i < 4; ++i) acc[m][i] = MFMA16(af[m], bw[i], acc[m][i]);
  }
#pragma unroll
  for (int m = 0; m < 2; ++m)
#pragma unroll
    for (int i = 0; i < 4; ++i) {
      const int col = 64 * w + 16 * i + l16;
      const float bv = bfv[col];
#pragma unroll
      for (int r = 0; r < 4; ++r) {
        const size_t R = (size_t)row0g + 16 * m + quad * 4 + r;
        __builtin_nontemporal_store(acc[m][i][r] + bv, outX + R * D_ + col);
      }
    }
}

// ---------------------------------------------------------------------------
// init: x -> xb bf16, xT bf16 (LDS 32x32 transpose), batch-contiguous XCD map.
// ---------------------------------------------------------------------------
__global__ __launch_bounds__(256) void init_x(
    const float* __restrict__ x, bf16* __restrict__ xb, bf16* __restrict__ xT)
{
  __shared__ float t[32 * 33];
  const int tid = threadIdx.x;
  const int wg = blockIdx.x;                 // 0..8191
  const int lid = (wg & 7) * 1024 + (wg >> 3);
  const int b = lid >> 7, rem = lid & 127;
  const int dt = rem >> 4, nt = rem & 15;
#pragma unroll
  for (int e = 0; e < 4; ++e) {
    const int idx = tid + e * 256;
    const int r = idx >> 5, c = idx & 31;
    const size_t g = ((size_t)(b * N_ + nt * 32 + r)) * D_ + dt * 32 + c;
    const float v = x[g];
    xb[g] = (bf16)v;
    t[r * 33 + c] = v;
  }
  __syncthreads();
#pragma unroll
  for (int e = 0; e < 4; ++e) {
    const int idx = tid + e * 256;
    const int r = idx >> 5, c = idx & 31;
    xT[((size_t)(b * D_ + dt * 32 + r)) * N_ + nt * 32 + c] = (bf16)t[c * 33 + r];
  }
}

extern "C" void kernel_launch(void* const* d_in, const int* in_sizes, int n_in,
                              void* d_out, int out_size, void* d_ws, size_t ws_size,
                              hipStream_t stream)
{
  const float* x_in  = (const float*)d_in[0];
  const float* adj   = (const float*)d_in[1];
  const float* wattn = (const float*)d_in[2];
  const float* battn = (const float*)d_in[3];
  const float* w0    = (const float*)d_in[4];
  const float* b0    = (const float*)d_in[5];
  const float* w1    = (const float*)d_in[6];
  const float* b1    = (const float*)d_in[7];
  const float* wf    = (const float*)d_in[8];
  const float* bfin  = (const float*)d_in[9];

  float* out_x    = (float*)d_out;                     // [B,N,D] f32 (final only)
  float* out_attn = out_x + (size_t)B_ * N_ * D_;      // [L,B,N,N]

  const size_t XBN = (size_t)B_ * N_ * D_;
  const int DD2 = D_ * D_;
  bf16* wb   = (bf16*)d_ws;                            // 13 * D*D packed weights
  bf16* xb0  = wb + 13 * DD2;
  bf16* xT0  = xb0 + XBN;
  bf16* xb1  = xT0 + XBN;
  bf16* xT1  = xb1 + XBN;
  bf16* xbpk = xT1 + XBN;                              // packed xb fragments
  bf16* xTpk = xbpk + XBN;                             // packed xT fragments
  unsigned short* bits = (unsigned short*)(xTpk + XBN);// [B,N,32] uint16
  bf16* q_ws = (bf16*)(bits + (size_t)B_ * N_ * 32);   // q / h (aliased)

  const int Mfull = B_ * N_;  // 32768

  // pack weights (f32 -> packed bf16 fragments); 32 blocks/matrix
  pack_w<<<dim3(4 * 32), 256, 0, stream>>>(wattn, wb);
  pack_w<<<dim3(4 * 32), 256, 0, stream>>>(w0, wb + 4 * DD2);
  pack_w<<<dim3(4 * 32), 256, 0, stream>>>(w1, wb + 8 * DD2);
  pack_w<<<dim3(1 * 32), 256, 0, stream>>>(wf, wb + 12 * DD2);

  init_x<<<dim3((N_ / 32) * (D_ / 32) * B_), 256, 0, stream>>>(x_in, xb0, xT0);
  pack_bf<<<dim3(4096), 256, 0, stream>>>(xb0, xbpk, 256, 3, 7);
  pack_bf<<<dim3(4096), 256, 0, stream>>>(xT0, xTpk, 512, 4, 15);

  bf16* xbs[2] = {xb0, xb1};
  bf16* xTs[2] = {xT0, xT1};
  for (int l = 0; l < L_; ++l) {
    const int pi = l & 1, po = 1 - pi;
    float* outA_l = out_attn + (size_t)l * B_ * N_ * N_;
    // q = x @ Wa^T + ba
    gemm_nt<false><<<dim3(Mfull / 64), 256, 0, stream>>>(
        xbs[pi], wb + l * DD2, battn + l * D_, q_ws);
    // P = sigmoid(q x^T) masked, normalized -> attls
    attn_kernel<<<dim3((N_ / 32) * B_), 256, 0, stream>>>(
        q_ws, xbpk, adj, (l == 0) ? nullptr : bits, (l == 0) ? bits : nullptr,
        outA_l);
    // x' = P @ x
    pv_gemm<<<dim3(Mfull / 64), 256, 0, stream>>>(outA_l, xTpk, xbs[po]);
    // h = relu(x' @ W0^T + b0)
    gemm_nt<true><<<dim3(Mfull / 64), 256, 0, stream>>>(
        xbs[po], wb + (4 + l) * DD2, b0 + l * D_, q_ws);
    // x = relu(h @ W1^T + b1) + x0 -> xb_out, xT_out
    l1_gemm<<<dim3(Mfull / 64), 256, 0, stream>>>(
        q_ws, wb + (8 + l) * DD2, b1 + l * D_, xTs[pi], xbs[po], xTs[po]);
    if (l < L_ - 1) {  // repack activations for next layer's attn/pv
      pack_bf<<<dim3(4096), 256, 0, stream>>>(xbs[po], xbpk, 256, 3, 7);
      pack_bf<<<dim3(4096), 256, 0, stream>>>(xTs[po], xTpk, 512, 4, 15);
    }
  }
  final_proj<<<dim3(Mfull / 32), 256, 0, stream>>>(xbs[0], wb + 12 * DD2, bfin, out_x);
}

// Round 6
// 792.781 us; speedup vs baseline: 1.2954x; 1.2103x over previous
//
#include <hip/hip_runtime.h>
#include <cstdint>

#define B_ 64
#define N_ 512
#define D_ 256
#define L_ 4

typedef __bf16 bf16;
typedef __attribute__((ext_vector_type(8))) __bf16 bf16x8;
typedef __attribute__((ext_vector_type(4))) __bf16 bf16x4;
typedef __attribute__((ext_vector_type(4))) float f32x4;

#define MFMA16(a, b, c) __builtin_amdgcn_mfma_f32_16x16x32_bf16((a), (b), (c), 0, 0, 0)

__device__ __forceinline__ float sigmoidf_(float z) {
  return 1.0f / (1.0f + __expf(-z));
}

// ===========================================================================
// R6: fused layer (R1's minimal-traffic 10-launch structure) + fully PACKED
// activations/weights (R5's dense 1KB-per-wave fragment loads) with zero
// separate pack kernels. Key fact: a packed unit's lane map (row=l16,
// k=quad*8+e) is simultaneously a valid MFMA A-fragment and B-fragment, so
// packed buffers serve p0's A, p1/p3's B, p5's residual, and are re-emitted
// packed by the p5 epilogue via an LDS transpose. Row-major activations no
// longer exist anywhere.
// Packed unit u = r16*KCS + kc: lane L holds src[r16*16+(L&15)][kc*32+
// (L>>4)*8 + e], e=0..7. xbpk: [b][n/16][d/32] KCS=8. xTpk: [b][d/16][n/32]
// KCS=16. W: [col/16][k/32] KCS=8.
// ===========================================================================

#define UIDX(u) (((size_t)(u)) * 64 + lane)

// ---------------------------------------------------------------------------
// pack_w: f32 row-major [nmat][256][256] -> packed bf16 fragments.
// ---------------------------------------------------------------------------
__global__ __launch_bounds__(256) void pack_w(
    const float* __restrict__ src, bf16* __restrict__ dst)
{
  const int tid = threadIdx.x, lane = tid & 63;
  const int U = blockIdx.x * 4 + (tid >> 6);
  const int m = U >> 7, u = U & 127;
  const int r16 = u >> 3, kc = u & 7;
  const int row = r16 * 16 + (lane & 15);
  const int k0 = kc * 32 + (lane >> 4) * 8;
  const float* s = src + (size_t)m * D_ * D_ + (size_t)row * D_ + k0;
  const float4 v0 = *(const float4*)s;
  const float4 v1 = *(const float4*)(s + 4);
  bf16x8 o;
  o[0] = (bf16)v0.x; o[1] = (bf16)v0.y; o[2] = (bf16)v0.z; o[3] = (bf16)v0.w;
  o[4] = (bf16)v1.x; o[5] = (bf16)v1.y; o[6] = (bf16)v1.z; o[7] = (bf16)v1.w;
  ((bf16x8*)dst)[(size_t)U * 64 + lane] = o;
}

// ---------------------------------------------------------------------------
// init_pack: f32 x -> xbpk + xTpk directly. 512 units/batch (256 xb, 256 xT).
// ---------------------------------------------------------------------------
__global__ __launch_bounds__(256) void init_pack(
    const float* __restrict__ x, bf16* __restrict__ xbpk, bf16* __restrict__ xTpk)
{
  const int tid = threadIdx.x, lane = tid & 63;
  const int U = blockIdx.x * 4 + (tid >> 6);    // 0..32767
  const int b = U >> 9, u = U & 511;
  if (u < 256) {            // xbpk unit: r16 = n/16, kc = d/32
    const int n = (u >> 3) * 16 + (lane & 15);
    const int d = (u & 7) * 32 + (lane >> 4) * 8;
    const float* s = x + ((size_t)(b * N_ + n)) * D_ + d;
    const float4 v0 = *(const float4*)s;
    const float4 v1 = *(const float4*)(s + 4);
    bf16x8 o;
    o[0] = (bf16)v0.x; o[1] = (bf16)v0.y; o[2] = (bf16)v0.z; o[3] = (bf16)v0.w;
    o[4] = (bf16)v1.x; o[5] = (bf16)v1.y; o[6] = (bf16)v1.z; o[7] = (bf16)v1.w;
    ((bf16x8*)xbpk)[((size_t)b * 256 + u) * 64 + lane] = o;
  } else {                  // xTpk unit: r16 = d/16, kc = n/32
    const int u2 = u - 256;
    const int d = (u2 >> 4) * 16 + (lane & 15);
    const int n = (u2 & 15) * 32 + (lane >> 4) * 8;
    bf16x8 o;
#pragma unroll
    for (int e = 0; e < 8; ++e)
      o[e] = (bf16)x[((size_t)(b * N_ + n + e)) * D_ + d];
    ((bf16x8*)xTpk)[((size_t)b * 256 + u2) * 64 + lane] = o;
  }
}

// ---------------------------------------------------------------------------
// gat_layer: one block per (32-row strip, batch); full layer fused; all
// global loads dense packed bursts. 8 barriers. LDS 52.9 KB -> 3 blocks/CU.
// ---------------------------------------------------------------------------
__global__ __launch_bounds__(256, 3) void gat_layer(
    const bf16* __restrict__ xbpk_in, const bf16* __restrict__ xTpk_in,
    bf16* __restrict__ xbpk_out, bf16* __restrict__ xTpk_out,
    const bf16* __restrict__ Wap, const float* __restrict__ ba,
    const bf16* __restrict__ W0p, const float* __restrict__ b0,
    const bf16* __restrict__ W1p, const float* __restrict__ b1,
    const float* __restrict__ adj, const unsigned short* __restrict__ bits_in,
    unsigned short* __restrict__ bits_out, float* __restrict__ outA)
{
  __shared__ bf16 qs[32 * 264];     // q / x' / resid-stage (stride 264)
  __shared__ bf16 xps[32 * 520];    // P (stride 520) / h, out-stage (stride 264)
  __shared__ float psum[4][32];
  __shared__ float rinvs[32];
  __shared__ unsigned int bits_s[512];

  const int tid = threadIdx.x, w = tid >> 6, lane = tid & 63;
  const int l16 = lane & 15, quad = lane >> 4;
  const int wg = blockIdx.x;
  const int lid = (wg & 7) * 128 + (wg >> 3);   // bijective XCD swizzle
  const int b = lid >> 4;
  const int row0 = (lid & 15) * 32;

  const bf16x8* Xbp = (const bf16x8*)xbpk_in + (size_t)b * 16384;
  const bf16x8* Xtp = (const bf16x8*)xTpk_in + (size_t)b * 16384;
  bf16x8* XbpO = (bf16x8*)xbpk_out + (size_t)b * 16384;
  bf16x8* XtpO = (bf16x8*)xTpk_out + (size_t)b * 16384;
  const bf16x8* Wa8 = (const bf16x8*)Wap;
  const bf16x8* W08 = (const bf16x8*)W0p;
  const bf16x8* W18 = (const bf16x8*)W1p;

  if (bits_in) {
#pragma unroll
    for (int e = 0; e < 2; ++e) {
      const int t = tid + e * 256;
      bits_s[t] = ((const unsigned int*)bits_in)[((size_t)b * N_ + row0) * 16 + t];
    }
  }

  // ---- p0: q = x @ Wa^T + ba ; A straight from packed global (dense) ----
  {
    f32x4 acc0[2][4] = {};
#pragma unroll
    for (int ks = 0; ks < 8; ++ks) {
      bf16x8 af[2];
#pragma unroll
      for (int m = 0; m < 2; ++m)
        af[m] = Xbp[UIDX(((row0 >> 4) + m) * 8 + ks)];
      bf16x8 bw[4];
#pragma unroll
      for (int i = 0; i < 4; ++i)
        bw[i] = Wa8[UIDX((4 * w + i) * 8 + ks)];
#pragma unroll
      for (int m = 0; m < 2; ++m)
#pragma unroll
        for (int i = 0; i < 4; ++i) acc0[m][i] = MFMA16(af[m], bw[i], acc0[m][i]);
    }
#pragma unroll
    for (int m = 0; m < 2; ++m)
#pragma unroll
      for (int i = 0; i < 4; ++i) {
        const int col = 64 * w + 16 * i + l16;
        const float bv = ba[col];
#pragma unroll
        for (int r = 0; r < 4; ++r)
          qs[(16 * m + quad * 4 + r) * 264 + col] = (bf16)(acc0[m][i][r] + bv);
      }
  }
  __syncthreads();   // b1: qs + bits_s ready

  // ---- p1: P = sigmoid(q @ x^T) masked -> xps; B dense packed ----
  float p[2][4] = {};
  bf16x8 afc[8][2];
#pragma unroll
  for (int ks = 0; ks < 8; ++ks)
#pragma unroll
    for (int m = 0; m < 2; ++m)
      afc[ks][m] = *(const bf16x8*)&qs[(16 * m + l16) * 264 + ks * 32 + quad * 8];

  for (int ct = 0; ct < 4; ++ct) {
    f32x4 acc1[2][2] = {};
#pragma unroll
    for (int ks = 0; ks < 8; ++ks) {
      bf16x8 bx[2];
#pragma unroll
      for (int jt = 0; jt < 2; ++jt)
        bx[jt] = Xbp[UIDX((ct * 8 + w * 2 + jt) * 8 + ks)];
#pragma unroll
      for (int m = 0; m < 2; ++m)
#pragma unroll
        for (int jt = 0; jt < 2; ++jt)
          acc1[m][jt] = MFMA16(afc[ks][m], bx[jt], acc1[m][jt]);
    }
#pragma unroll
    for (int jt = 0; jt < 2; ++jt) {
      const int lcol = ct * 128 + w * 32 + jt * 16 + l16;
      const int piece = ct * 8 + w * 2 + jt;
#pragma unroll
      for (int m = 0; m < 2; ++m)
#pragma unroll
        for (int r = 0; r < 4; ++r) {
          const int row = 16 * m + quad * 4 + r;
          const int grow = row0 + row;
          float av;
          if (bits_in) {
            const unsigned short m16 = ((const unsigned short*)bits_s)[row * 32 + piece];
            av = (float)((m16 >> l16) & 1);
          } else {
            av = __builtin_nontemporal_load(
                adj + ((size_t)b * N_ + grow) * N_ + lcol);
          }
          const bool diag = (grow == lcol);
          if (bits_out) {
            const unsigned long long bal = __ballot(diag || av != 0.0f);
            if (l16 == 0)
              bits_out[((size_t)b * N_ + row0 + 16 * m + 4 * quad + r) * 32 + piece] =
                  (unsigned short)((bal >> (quad * 16)) & 0xFFFFull);
          }
          const float sg = sigmoidf_(acc1[m][jt][r]);
          const float v = diag ? (sg + 1e-5f) : sg * av;
          const bf16 bv = (bf16)v;
          xps[row * 520 + lcol] = bv;
          p[m][r] += (float)bv;
        }
    }
  }
#pragma unroll
  for (int m = 0; m < 2; ++m)
#pragma unroll
    for (int r = 0; r < 4; ++r) {
#pragma unroll
      for (int msk = 1; msk < 16; msk <<= 1) p[m][r] += __shfl_xor(p[m][r], msk, 64);
    }
  if (l16 == 0) {
#pragma unroll
    for (int m = 0; m < 2; ++m)
#pragma unroll
      for (int r = 0; r < 4; ++r) psum[w][16 * m + quad * 4 + r] = p[m][r];
  }
  __syncthreads();   // b2
  if (tid < 32)
    rinvs[tid] = 1.0f / (psum[0][tid] + psum[1][tid] + psum[2][tid] + psum[3][tid]);
  __syncthreads();   // b3

  // ---- p2: normalize; attls f32 NT out; normalized bf16 back to xps ----
  const size_t abase = ((size_t)b * N_ + row0) * N_;
#pragma unroll
  for (int e = 0; e < 16; ++e) {
    const int idx = tid + e * 256;
    const int row = idx >> 7, c4 = (idx & 127) * 4;
    const float ri = rinvs[row];
    bf16x4 pv = *(const bf16x4*)&xps[row * 520 + c4];
    f32x4 nv;
    nv[0] = (float)pv[0] * ri; nv[1] = (float)pv[1] * ri;
    nv[2] = (float)pv[2] * ri; nv[3] = (float)pv[3] * ri;
    __builtin_nontemporal_store(nv, (f32x4*)(outA + abase + (size_t)row * N_ + c4));
    bf16x4 o;
    o[0] = (bf16)nv[0]; o[1] = (bf16)nv[1]; o[2] = (bf16)nv[2]; o[3] = (bf16)nv[3];
    *(bf16x4*)&xps[row * 520 + c4] = o;
  }
  __syncthreads();   // b4

  // ---- p3: x' = P @ x (B = xTpk dense), K = 512 -> qs ----
  {
    f32x4 acc3[2][4] = {};
#pragma unroll
    for (int ks = 0; ks < 16; ++ks) {
      bf16x8 af[2];
#pragma unroll
      for (int m = 0; m < 2; ++m)
        af[m] = *(const bf16x8*)&xps[(16 * m + l16) * 520 + ks * 32 + quad * 8];
      bf16x8 bt[4];
#pragma unroll
      for (int i = 0; i < 4; ++i)
        bt[i] = Xtp[UIDX((4 * w + i) * 16 + ks)];
#pragma unroll
      for (int m = 0; m < 2; ++m)
#pragma unroll
        for (int i = 0; i < 4; ++i) acc3[m][i] = MFMA16(af[m], bt[i], acc3[m][i]);
    }
#pragma unroll
    for (int m = 0; m < 2; ++m)
#pragma unroll
      for (int i = 0; i < 4; ++i) {
        const int d = 64 * w + 16 * i + l16;
#pragma unroll
        for (int r = 0; r < 4; ++r)
          qs[(16 * m + quad * 4 + r) * 264 + d] = (bf16)acc3[m][i][r];
      }
  }
  __syncthreads();   // b5

  // ---- p4: h = relu(x' @ W0^T + b0) -> xps (stride 264) ----
  {
    f32x4 acc[2][4] = {};
#pragma unroll
    for (int ks = 0; ks < 8; ++ks) {
      bf16x8 af[2];
#pragma unroll
      for (int m = 0; m < 2; ++m)
        af[m] = *(const bf16x8*)&qs[(16 * m + l16) * 264 + ks * 32 + quad * 8];
      bf16x8 bw[4];
#pragma unroll
      for (int i = 0; i < 4; ++i)
        bw[i] = W08[UIDX((4 * w + i) * 8 + ks)];
#pragma unroll
      for (int m = 0; m < 2; ++m)
#pragma unroll
        for (int i = 0; i < 4; ++i) acc[m][i] = MFMA16(af[m], bw[i], acc[m][i]);
    }
#pragma unroll
    for (int m = 0; m < 2; ++m)
#pragma unroll
      for (int i = 0; i < 4; ++i) {
        const int col = 64 * w + 16 * i + l16;
        const float bv = b0[col];
#pragma unroll
        for (int r = 0; r < 4; ++r)
          xps[(16 * m + quad * 4 + r) * 264 + col] = (bf16)fmaxf(acc[m][i][r] + bv, 0.0f);
      }
  }
  __syncthreads();   // b6

  // ---- p5: x = relu(h @ W1^T + b1) + resid; emit packed outputs ----
  {
    // hoist h (A) to regs; then xps becomes the output staging buffer
    bf16x8 ah[8][2];
#pragma unroll
    for (int ks = 0; ks < 8; ++ks)
#pragma unroll
      for (int m = 0; m < 2; ++m)
        ah[ks][m] = *(const bf16x8*)&xps[(16 * m + l16) * 264 + ks * 32 + quad * 8];
    // stage residual strip from packed xb_in into qs (dense loads)
#pragma unroll
    for (int j = 0; j < 4; ++j) {
      const int t = w * 4 + j;
      const bf16x8 v = Xbp[UIDX(((row0 >> 4) + (t >> 3)) * 8 + (t & 7))];
      const int nl = (t >> 3) * 16 + l16, dd = (t & 7) * 32 + quad * 8;
      *(bf16x8*)&qs[nl * 264 + dd] = v;
    }
    __syncthreads();   // b7: resid staged, all h-hoists complete

    f32x4 acc[2][4] = {};
#pragma unroll
    for (int ks = 0; ks < 8; ++ks) {
      bf16x8 bw[4];
#pragma unroll
      for (int i = 0; i < 4; ++i)
        bw[i] = W18[UIDX((4 * w + i) * 8 + ks)];
#pragma unroll
      for (int m = 0; m < 2; ++m)
#pragma unroll
        for (int i = 0; i < 4; ++i) acc[m][i] = MFMA16(ah[ks][m], bw[i], acc[m][i]);
    }
#pragma unroll
    for (int m = 0; m < 2; ++m)
#pragma unroll
      for (int i = 0; i < 4; ++i) {
        const int d = 64 * w + 16 * i + l16;
        const float bv = b1[d];
#pragma unroll
        for (int r = 0; r < 4; ++r) {
          const int nl = 16 * m + quad * 4 + r;
          const float x0 = (float)qs[nl * 264 + d];
          const float t2 = fmaxf(acc[m][i][r] + bv, 0.0f) + x0;
          xps[nl * 264 + d] = (bf16)t2;
        }
      }
    __syncthreads();   // b8: output strip staged in xps [32][264]

    // packed xb_out: 16 units, dense 1KB stores
#pragma unroll
    for (int j = 0; j < 4; ++j) {
      const int t = w * 4 + j;
      const int nl = (t >> 3) * 16 + l16, dd = (t & 7) * 32 + quad * 8;
      const bf16x8 v = *(const bf16x8*)&xps[nl * 264 + dd];
      XbpO[UIDX(((row0 >> 4) + (t >> 3)) * 8 + (t & 7))] = v;
    }
    // packed xT_out: 16 units (LDS transpose reads), dense 1KB stores
#pragma unroll
    for (int j = 0; j < 4; ++j) {
      const int t = w * 4 + j;
      const int dd = t * 16 + l16;
      bf16x8 v;
#pragma unroll
      for (int e = 0; e < 8; ++e)
        v[e] = xps[(quad * 8 + e) * 264 + dd];
      XtpO[UIDX(t * 16 + (row0 >> 5))] = v;
    }
  }
}

// ---------------------------------------------------------------------------
// final_proj: out = x @ Wf^T + bf (f32). A from packed xb (dense), no LDS.
// ---------------------------------------------------------------------------
__global__ __launch_bounds__(256, 4) void final_proj(
    const bf16* __restrict__ xbpk, const bf16* __restrict__ Wfp,
    const float* __restrict__ bfv, float* __restrict__ outX)
{
  const int tid = threadIdx.x, w = tid >> 6, lane = tid & 63;
  const int l16 = lane & 15, quad = lane >> 4;
  const int wg = blockIdx.x;
  const int lid = (wg & 7) * 128 + (wg >> 3);
  const int row0g = lid * 32;
  const int b = row0g >> 9, n0 = row0g & 511;
  const bf16x8* Xbp = (const bf16x8*)xbpk + (size_t)b * 16384;
  const bf16x8* Wf8 = (const bf16x8*)Wfp;
  f32x4 acc[2][4] = {};
#pragma unroll
  for (int ks = 0; ks < 8; ++ks) {
    bf16x8 af[2];
#pragma unroll
    for (int m = 0; m < 2; ++m)
      af[m] = Xbp[UIDX(((n0 >> 4) + m) * 8 + ks)];
    bf16x8 bw[4];
#pragma unroll
    for (int i = 0; i < 4; ++i)
      bw[i] = Wf8[UIDX((4 * w + i) * 8 + ks)];
#pragma unroll
    for (int m = 0; m < 2; ++m)
#pragma unroll
      for (int i = 0; i < 4; ++i) acc[m][i] = MFMA16(af[m], bw[i], acc[m][i]);
  }
#pragma unroll
  for (int m = 0; m < 2; ++m)
#pragma unroll
    for (int i = 0; i < 4; ++i) {
      const int col = 64 * w + 16 * i + l16;
      const float bv = bfv[col];
#pragma unroll
      for (int r = 0; r < 4; ++r) {
        const size_t R = (size_t)row0g + 16 * m + quad * 4 + r;
        __builtin_nontemporal_store(acc[m][i][r] + bv, outX + R * D_ + col);
      }
    }
}

extern "C" void kernel_launch(void* const* d_in, const int* in_sizes, int n_in,
                              void* d_out, int out_size, void* d_ws, size_t ws_size,
                              hipStream_t stream)
{
  const float* x_in  = (const float*)d_in[0];
  const float* adj   = (const float*)d_in[1];
  const float* wattn = (const float*)d_in[2];
  const float* battn = (const float*)d_in[3];
  const float* w0    = (const float*)d_in[4];
  const float* b0    = (const float*)d_in[5];
  const float* w1    = (const float*)d_in[6];
  const float* b1    = (const float*)d_in[7];
  const float* wf    = (const float*)d_in[8];
  const float* bfin  = (const float*)d_in[9];

  float* out_x    = (float*)d_out;                     // [B,N,D] f32
  float* out_attn = out_x + (size_t)B_ * N_ * D_;      // [L,B,N,N]

  const size_t XBN = (size_t)B_ * N_ * D_;
  const int DD2 = D_ * D_;
  bf16* wb   = (bf16*)d_ws;                            // 13*D*D packed weights
  bf16* xbp0 = wb + 13 * DD2;
  bf16* xtp0 = xbp0 + XBN;
  bf16* xbp1 = xtp0 + XBN;
  bf16* xtp1 = xbp1 + XBN;
  unsigned short* bits = (unsigned short*)(xtp1 + XBN);// [B,N,32] uint16

  // pack weights (f32 -> packed bf16 fragments)
  pack_w<<<dim3(4 * 32), 256, 0, stream>>>(wattn, wb);
  pack_w<<<dim3(4 * 32), 256, 0, stream>>>(w0, wb + 4 * DD2);
  pack_w<<<dim3(4 * 32), 256, 0, stream>>>(w1, wb + 8 * DD2);
  pack_w<<<dim3(1 * 32), 256, 0, stream>>>(wf, wb + 12 * DD2);

  // x -> packed xb + packed xT
  init_pack<<<dim3(8192), 256, 0, stream>>>(x_in, xbp0, xtp0);

  bf16* xbps[2] = {xbp0, xbp1};
  bf16* xtps[2] = {xtp0, xtp1};
  for (int l = 0; l < L_; ++l) {
    const int pi = l & 1, po = 1 - pi;
    gat_layer<<<dim3((N_ / 32) * B_), 256, 0, stream>>>(
        xbps[pi], xtps[pi], xbps[po], xtps[po],
        wb + l * DD2, battn + l * D_,
        wb + (4 + l) * DD2, b0 + l * D_,
        wb + (8 + l) * DD2, b1 + l * D_,
        adj, (l == 0) ? nullptr : bits, (l == 0) ? bits : nullptr,
        out_attn + (size_t)l * B_ * N_ * N_);
  }
  final_proj<<<dim3((B_ * N_) / 32), 256, 0, stream>>>(
      xbps[0], wb + 12 * DD2, bfin, out_x);
}

// Round 8
// 725.007 us; speedup vs baseline: 1.4165x; 1.0935x over previous
//
#include <hip/hip_runtime.h>
#include <cstdint>

#define B_ 64
#define N_ 512
#define D_ 256
#define L_ 4

typedef __bf16 bf16;
typedef __attribute__((ext_vector_type(8))) __bf16 bf16x8;
typedef __attribute__((ext_vector_type(4))) __bf16 bf16x4;
typedef __attribute__((ext_vector_type(4))) float f32x4;

#define MFMA16(a, b, c) __builtin_amdgcn_mfma_f32_16x16x32_bf16((a), (b), (c), 0, 0, 0)

__device__ __forceinline__ float sigmoidf_(float z) {
  return 1.0f / (1.0f + __expf(-z));
}

// ===========================================================================
// R8 = R7 resubmit (container-acquire failure last round; kernel never ran).
// R7: R6 (fused layer, fully packed fragment I/O) + 64-ROW strips at 512
// threads, 1 block/CU. Rationale (latency-capacity model): per-layer stall
// ~ streamed-lines x miss-latency / MSHRs. Each block streams the whole
// batch xb+xT+weights regardless of strip height, so doubling M halves the
// block count and total line demand, and shrinks the concurrent per-XCD
// working set to ~2.4MB (< 4MB L2) so misses get L2 latency, not L3.
// Packed unit u: lane L holds src[r16*16+(L&15)][kc*32+(L>>4)*8+e], e=0..7;
// valid as both MFMA A- and B-fragment. xbpk: [b][n/16][d/32] KCS=8.
// xTpk: [b][d/16][n/32] KCS=16. W: [col/16][k/32] KCS=8.
// ===========================================================================

#define UIDX(u) (((size_t)(u)) * 64 + lane)

// ---------------------------------------------------------------------------
// pack_w: f32 row-major [nmat][256][256] -> packed bf16 fragments.
// ---------------------------------------------------------------------------
__global__ __launch_bounds__(256) void pack_w(
    const float* __restrict__ src, bf16* __restrict__ dst)
{
  const int tid = threadIdx.x, lane = tid & 63;
  const int U = blockIdx.x * 4 + (tid >> 6);
  const int m = U >> 7, u = U & 127;
  const int r16 = u >> 3, kc = u & 7;
  const int row = r16 * 16 + (lane & 15);
  const int k0 = kc * 32 + (lane >> 4) * 8;
  const float* s = src + (size_t)m * D_ * D_ + (size_t)row * D_ + k0;
  const float4 v0 = *(const float4*)s;
  const float4 v1 = *(const float4*)(s + 4);
  bf16x8 o;
  o[0] = (bf16)v0.x; o[1] = (bf16)v0.y; o[2] = (bf16)v0.z; o[3] = (bf16)v0.w;
  o[4] = (bf16)v1.x; o[5] = (bf16)v1.y; o[6] = (bf16)v1.z; o[7] = (bf16)v1.w;
  ((bf16x8*)dst)[(size_t)U * 64 + lane] = o;
}

// ---------------------------------------------------------------------------
// init_pack: f32 x -> xbpk + xTpk directly.
// ---------------------------------------------------------------------------
__global__ __launch_bounds__(256) void init_pack(
    const float* __restrict__ x, bf16* __restrict__ xbpk, bf16* __restrict__ xTpk)
{
  const int tid = threadIdx.x, lane = tid & 63;
  const int U = blockIdx.x * 4 + (tid >> 6);    // 0..32767
  const int b = U >> 9, u = U & 511;
  if (u < 256) {            // xbpk unit: r16 = n/16, kc = d/32
    const int n = (u >> 3) * 16 + (lane & 15);
    const int d = (u & 7) * 32 + (lane >> 4) * 8;
    const float* s = x + ((size_t)(b * N_ + n)) * D_ + d;
    const float4 v0 = *(const float4*)s;
    const float4 v1 = *(const float4*)(s + 4);
    bf16x8 o;
    o[0] = (bf16)v0.x; o[1] = (bf16)v0.y; o[2] = (bf16)v0.z; o[3] = (bf16)v0.w;
    o[4] = (bf16)v1.x; o[5] = (bf16)v1.y; o[6] = (bf16)v1.z; o[7] = (bf16)v1.w;
    ((bf16x8*)xbpk)[((size_t)b * 256 + u) * 64 + lane] = o;
  } else {                  // xTpk unit: r16 = d/16, kc = n/32
    const int u2 = u - 256;
    const int d = (u2 >> 4) * 16 + (lane & 15);
    const int n = (u2 & 15) * 32 + (lane >> 4) * 8;
    bf16x8 o;
#pragma unroll
    for (int e = 0; e < 8; ++e)
      o[e] = (bf16)x[((size_t)(b * N_ + n + e)) * D_ + d];
    ((bf16x8*)xTpk)[((size_t)b * 256 + u2) * 64 + lane] = o;
  }
}

// ---------------------------------------------------------------------------
// gat_layer: one block per (64-row strip, batch); 512 threads (8 waves);
// full layer fused; all global loads dense packed bursts. 8 barriers.
// LDS ~104 KB -> 1 block/CU. Grid 512.
// ---------------------------------------------------------------------------
__global__ __launch_bounds__(512, 1) void gat_layer(
    const bf16* __restrict__ xbpk_in, const bf16* __restrict__ xTpk_in,
    bf16* __restrict__ xbpk_out, bf16* __restrict__ xTpk_out,
    const bf16* __restrict__ Wap, const float* __restrict__ ba,
    const bf16* __restrict__ W0p, const float* __restrict__ b0,
    const bf16* __restrict__ W1p, const float* __restrict__ b1,
    const float* __restrict__ adj, const unsigned short* __restrict__ bits_in,
    unsigned short* __restrict__ bits_out, float* __restrict__ outA)
{
  __shared__ bf16 qs[64 * 264];     // q / x' / out-stage (stride 264)  33.8KB
  __shared__ bf16 xps[64 * 520];    // P (stride 520) / h (stride 264)  66.6KB
  __shared__ float psum[8][64];     //                                   2KB
  __shared__ float rinvs[64];
  __shared__ unsigned int bits_s[1024];  // 64 rows x 32 uint16          4KB

  const int tid = threadIdx.x, w = tid >> 6, lane = tid & 63;
  const int l16 = lane & 15, quad = lane >> 4;
  const int wg = blockIdx.x;
  const int lid = (wg & 7) * 64 + (wg >> 3);   // bijective XCD swizzle
  const int b = lid >> 3;                      // 8 strips per batch
  const int row0 = (lid & 7) * 64;

  const bf16x8* Xbp = (const bf16x8*)xbpk_in + (size_t)b * 16384;
  const bf16x8* Xtp = (const bf16x8*)xTpk_in + (size_t)b * 16384;
  bf16x8* XbpO = (bf16x8*)xbpk_out + (size_t)b * 16384;
  bf16x8* XtpO = (bf16x8*)xTpk_out + (size_t)b * 16384;
  const bf16x8* Wa8 = (const bf16x8*)Wap;
  const bf16x8* W08 = (const bf16x8*)W0p;
  const bf16x8* W18 = (const bf16x8*)W1p;

  if (bits_in) {
#pragma unroll
    for (int e = 0; e < 2; ++e) {
      const int t = tid + e * 512;
      bits_s[t] = ((const unsigned int*)bits_in)[((size_t)b * N_ + row0) * 16 + t];
    }
  }

  // ---- p0: q = x @ Wa^T + ba ; A straight from packed global (dense) ----
  // wave w -> cols [32w, 32w+32)
  {
    f32x4 acc0[4][2] = {};
#pragma unroll
    for (int ks = 0; ks < 8; ++ks) {
      bf16x8 af[4];
#pragma unroll
      for (int m = 0; m < 4; ++m)
        af[m] = Xbp[UIDX(((row0 >> 4) + m) * 8 + ks)];
      bf16x8 bw[2];
#pragma unroll
      for (int i = 0; i < 2; ++i)
        bw[i] = Wa8[UIDX((2 * w + i) * 8 + ks)];
#pragma unroll
      for (int m = 0; m < 4; ++m)
#pragma unroll
        for (int i = 0; i < 2; ++i) acc0[m][i] = MFMA16(af[m], bw[i], acc0[m][i]);
    }
#pragma unroll
    for (int m = 0; m < 4; ++m)
#pragma unroll
      for (int i = 0; i < 2; ++i) {
        const int col = 32 * w + 16 * i + l16;
        const float bv = ba[col];
#pragma unroll
        for (int r = 0; r < 4; ++r)
          qs[(16 * m + quad * 4 + r) * 264 + col] = (bf16)(acc0[m][i][r] + bv);
      }
  }
  __syncthreads();   // b1: qs(q) + bits_s ready

  // ---- p1: P = sigmoid(q @ x^T) masked -> xps; wave w -> cols [64w,64w+64)
  float p[4][4] = {};
  {
    f32x4 acc1[4][4] = {};
#pragma unroll
    for (int ks = 0; ks < 8; ++ks) {
      bf16x8 af[4];
#pragma unroll
      for (int m = 0; m < 4; ++m)
        af[m] = *(const bf16x8*)&qs[(16 * m + l16) * 264 + ks * 32 + quad * 8];
      bf16x8 bx[4];
#pragma unroll
      for (int jt = 0; jt < 4; ++jt)
        bx[jt] = Xbp[UIDX((4 * w + jt) * 8 + ks)];
#pragma unroll
      for (int m = 0; m < 4; ++m)
#pragma unroll
        for (int jt = 0; jt < 4; ++jt)
          acc1[m][jt] = MFMA16(af[m], bx[jt], acc1[m][jt]);
    }
#pragma unroll
    for (int jt = 0; jt < 4; ++jt) {
      const int lcol = 64 * w + jt * 16 + l16;
      const int piece = 4 * w + jt;
#pragma unroll
      for (int m = 0; m < 4; ++m)
#pragma unroll
        for (int r = 0; r < 4; ++r) {
          const int row = 16 * m + quad * 4 + r;
          const int grow = row0 + row;
          float av;
          if (bits_in) {
            const unsigned short m16 = ((const unsigned short*)bits_s)[row * 32 + piece];
            av = (float)((m16 >> l16) & 1);
          } else {
            av = __builtin_nontemporal_load(
                adj + ((size_t)b * N_ + grow) * N_ + lcol);
          }
          const bool diag = (grow == lcol);
          if (bits_out) {
            const unsigned long long bal = __ballot(diag || av != 0.0f);
            if (l16 == 0)
              bits_out[((size_t)b * N_ + row0 + 16 * m + 4 * quad + r) * 32 + piece] =
                  (unsigned short)((bal >> (quad * 16)) & 0xFFFFull);
          }
          const float sg = sigmoidf_(acc1[m][jt][r]);
          const float v = diag ? (sg + 1e-5f) : sg * av;
          const bf16 bv = (bf16)v;
          xps[row * 520 + lcol] = bv;
          p[m][r] += (float)bv;
        }
    }
  }
#pragma unroll
  for (int m = 0; m < 4; ++m)
#pragma unroll
    for (int r = 0; r < 4; ++r) {
#pragma unroll
      for (int msk = 1; msk < 16; msk <<= 1) p[m][r] += __shfl_xor(p[m][r], msk, 64);
    }
  if (l16 == 0) {
#pragma unroll
    for (int m = 0; m < 4; ++m)
#pragma unroll
      for (int r = 0; r < 4; ++r) psum[w][16 * m + quad * 4 + r] = p[m][r];
  }
  __syncthreads();   // b2
  if (tid < 64) {
    float s = 0.0f;
#pragma unroll
    for (int ww = 0; ww < 8; ++ww) s += psum[ww][tid];
    rinvs[tid] = 1.0f / s;
  }
  __syncthreads();   // b3

  // ---- p2: normalize; attls f32 NT out; normalized bf16 back to xps ----
  const size_t abase = ((size_t)b * N_ + row0) * N_;
#pragma unroll
  for (int e = 0; e < 16; ++e) {
    const int idx = tid + e * 512;
    const int row = idx >> 7, c4 = (idx & 127) * 4;
    const float ri = rinvs[row];
    bf16x4 pv = *(const bf16x4*)&xps[row * 520 + c4];
    f32x4 nv;
    nv[0] = (float)pv[0] * ri; nv[1] = (float)pv[1] * ri;
    nv[2] = (float)pv[2] * ri; nv[3] = (float)pv[3] * ri;
    __builtin_nontemporal_store(nv, (f32x4*)(outA + abase + (size_t)row * N_ + c4));
    bf16x4 o;
    o[0] = (bf16)nv[0]; o[1] = (bf16)nv[1]; o[2] = (bf16)nv[2]; o[3] = (bf16)nv[3];
    *(bf16x4*)&xps[row * 520 + c4] = o;
  }
  __syncthreads();   // b4

  // ---- p3: x' = P @ x (B = xTpk dense), K = 512 -> qs ----
  {
    f32x4 acc3[4][2] = {};
#pragma unroll
    for (int ks = 0; ks < 16; ++ks) {
      bf16x8 af[4];
#pragma unroll
      for (int m = 0; m < 4; ++m)
        af[m] = *(const bf16x8*)&xps[(16 * m + l16) * 520 + ks * 32 + quad * 8];
      bf16x8 bt[2];
#pragma unroll
      for (int i = 0; i < 2; ++i)
        bt[i] = Xtp[UIDX((2 * w + i) * 16 + ks)];
#pragma unroll
      for (int m = 0; m < 4; ++m)
#pragma unroll
        for (int i = 0; i < 2; ++i) acc3[m][i] = MFMA16(af[m], bt[i], acc3[m][i]);
    }
#pragma unroll
    for (int m = 0; m < 4; ++m)
#pragma unroll
      for (int i = 0; i < 2; ++i) {
        const int d = 32 * w + 16 * i + l16;
#pragma unroll
        for (int r = 0; r < 4; ++r)
          qs[(16 * m + quad * 4 + r) * 264 + d] = (bf16)acc3[m][i][r];
      }
  }
  __syncthreads();   // b5

  // ---- p4: h = relu(x' @ W0^T + b0) -> xps (stride 264) ----
  {
    f32x4 acc[4][2] = {};
#pragma unroll
    for (int ks = 0; ks < 8; ++ks) {
      bf16x8 af[4];
#pragma unroll
      for (int m = 0; m < 4; ++m)
        af[m] = *(const bf16x8*)&qs[(16 * m + l16) * 264 + ks * 32 + quad * 8];
      bf16x8 bw[2];
#pragma unroll
      for (int i = 0; i < 2; ++i)
        bw[i] = W08[UIDX((2 * w + i) * 8 + ks)];
#pragma unroll
      for (int m = 0; m < 4; ++m)
#pragma unroll
        for (int i = 0; i < 2; ++i) acc[m][i] = MFMA16(af[m], bw[i], acc[m][i]);
    }
#pragma unroll
    for (int m = 0; m < 4; ++m)
#pragma unroll
      for (int i = 0; i < 2; ++i) {
        const int col = 32 * w + 16 * i + l16;
        const float bv = b0[col];
#pragma unroll
        for (int r = 0; r < 4; ++r)
          xps[(16 * m + quad * 4 + r) * 264 + col] = (bf16)fmaxf(acc[m][i][r] + bv, 0.0f);
      }
  }
  __syncthreads();   // b6: h in xps; qs (x') dead

  // ---- p5: x = relu(h @ W1^T + b1) + resid; emit packed outputs ----
  {
    // stage residual strip from packed xb_in into qs (dense loads)
#pragma unroll
    for (int j = 0; j < 4; ++j) {
      const int uu = w * 4 + j;
      const int rr = uu >> 3, kc = uu & 7;
      const bf16x8 v = Xbp[UIDX(((row0 >> 4) + rr) * 8 + kc)];
      *(bf16x8*)&qs[(rr * 16 + l16) * 264 + kc * 32 + quad * 8] = v;
    }
    // MFMA loop reads only xps (h) + W1 global
    f32x4 acc[4][2] = {};
#pragma unroll
    for (int ks = 0; ks < 8; ++ks) {
      bf16x8 af[4];
#pragma unroll
      for (int m = 0; m < 4; ++m)
        af[m] = *(const bf16x8*)&xps[(16 * m + l16) * 264 + ks * 32 + quad * 8];
      bf16x8 bw[2];
#pragma unroll
      for (int i = 0; i < 2; ++i)
        bw[i] = W18[UIDX((2 * w + i) * 8 + ks)];
#pragma unroll
      for (int m = 0; m < 4; ++m)
#pragma unroll
        for (int i = 0; i < 2; ++i) acc[m][i] = MFMA16(af[m], bw[i], acc[m][i]);
    }
    __syncthreads();   // b7: resid staged in qs (cross-thread) visible

#pragma unroll
    for (int m = 0; m < 4; ++m)
#pragma unroll
      for (int i = 0; i < 2; ++i) {
        const int d = 32 * w + 16 * i + l16;
        const float bv = b1[d];
#pragma unroll
        for (int r = 0; r < 4; ++r) {
          const int nl = 16 * m + quad * 4 + r;
          const float x0 = (float)qs[nl * 264 + d];
          const float t2 = fmaxf(acc[m][i][r] + bv, 0.0f) + x0;
          qs[nl * 264 + d] = (bf16)t2;   // own cell: read-then-write, no race
        }
      }
    __syncthreads();   // b8: output strip staged in qs [64][264]

    // packed xb_out: 32 units, dense 1KB stores
#pragma unroll
    for (int j = 0; j < 4; ++j) {
      const int uu = w * 4 + j;
      const int rr = uu >> 3, kc = uu & 7;
      const bf16x8 v = *(const bf16x8*)&qs[(rr * 16 + l16) * 264 + kc * 32 + quad * 8];
      XbpO[UIDX(((row0 >> 4) + rr) * 8 + kc)] = v;
    }
    // packed xT_out: 32 units (LDS transpose reads), dense 1KB stores
#pragma unroll
    for (int j = 0; j < 4; ++j) {
      const int uu = w * 4 + j;
      const int d16 = uu >> 1, nk = uu & 1;
      const int d = d16 * 16 + l16;
      bf16x8 v;
#pragma unroll
      for (int e = 0; e < 8; ++e)
        v[e] = qs[(nk * 32 + quad * 8 + e) * 264 + d];
      XtpO[UIDX(d16 * 16 + (row0 >> 5) + nk)] = v;
    }
  }
}

// ---------------------------------------------------------------------------
// final_proj: out = x @ Wf^T + bf (f32). A from packed xb (dense), no LDS.
// ---------------------------------------------------------------------------
__global__ __launch_bounds__(256, 4) void final_proj(
    const bf16* __restrict__ xbpk, const bf16* __restrict__ Wfp,
    const float* __restrict__ bfv, float* __restrict__ outX)
{
  const int tid = threadIdx.x, w = tid >> 6, lane = tid & 63;
  const int l16 = lane & 15, quad = lane >> 4;
  const int wg = blockIdx.x;
  const int lid = (wg & 7) * 128 + (wg >> 3);
  const int row0g = lid * 32;
  const int b = row0g >> 9, n0 = row0g & 511;
  const bf16x8* Xbp = (const bf16x8*)xbpk + (size_t)b * 16384;
  const bf16x8* Wf8 = (const bf16x8*)Wfp;
  f32x4 acc[2][4] = {};
#pragma unroll
  for (int ks = 0; ks < 8; ++ks) {
    bf16x8 af[2];
#pragma unroll
    for (int m = 0; m < 2; ++m)
      af[m] = Xbp[UIDX(((n0 >> 4) + m) * 8 + ks)];
    bf16x8 bw[4];
#pragma unroll
    for (int i = 0; i < 4; ++i)
      bw[i] = Wf8[UIDX((4 * w + i) * 8 + ks)];
#pragma unroll
    for (int m = 0; m < 2; ++m)
#pragma unroll
      for (int i = 0; i < 4; ++i) acc[m][i] = MFMA16(af[m], bw[i], acc[m][i]);
  }
#pragma unroll
  for (int m = 0; m < 2; ++m)
#pragma unroll
    for (int i = 0; i < 4; ++i) {
      const int col = 64 * w + 16 * i + l16;
      const float bv = bfv[col];
#pragma unroll
      for (int r = 0; r < 4; ++r) {
        const size_t R = (size_t)row0g + 16 * m + quad * 4 + r;
        __builtin_nontemporal_store(acc[m][i][r] + bv, outX + R * D_ + col);
      }
    }
}

extern "C" void kernel_launch(void* const* d_in, const int* in_sizes, int n_in,
                              void* d_out, int out_size, void* d_ws, size_t ws_size,
                              hipStream_t stream)
{
  const float* x_in  = (const float*)d_in[0];
  const float* adj   = (const float*)d_in[1];
  const float* wattn = (const float*)d_in[2];
  const float* battn = (const float*)d_in[3];
  const float* w0    = (const float*)d_in[4];
  const float* b0    = (const float*)d_in[5];
  const float* w1    = (const float*)d_in[6];
  const float* b1    = (const float*)d_in[7];
  const float* wf    = (const float*)d_in[8];
  const float* bfin  = (const float*)d_in[9];

  float* out_x    = (float*)d_out;                     // [B,N,D] f32
  float* out_attn = out_x + (size_t)B_ * N_ * D_;      // [L,B,N,N]

  const size_t XBN = (size_t)B_ * N_ * D_;
  const int DD2 = D_ * D_;
  bf16* wb   = (bf16*)d_ws;                            // 13*D*D packed weights
  bf16* xbp0 = wb + 13 * DD2;
  bf16* xtp0 = xbp0 + XBN;
  bf16* xbp1 = xtp0 + XBN;
  bf16* xtp1 = xbp1 + XBN;
  unsigned short* bits = (unsigned short*)(xtp1 + XBN);// [B,N,32] uint16

  // pack weights (f32 -> packed bf16 fragments)
  pack_w<<<dim3(4 * 32), 256, 0, stream>>>(wattn, wb);
  pack_w<<<dim3(4 * 32), 256, 0, stream>>>(w0, wb + 4 * DD2);
  pack_w<<<dim3(4 * 32), 256, 0, stream>>>(w1, wb + 8 * DD2);
  pack_w<<<dim3(1 * 32), 256, 0, stream>>>(wf, wb + 12 * DD2);

  // x -> packed xb + packed xT
  init_pack<<<dim3(8192), 256, 0, stream>>>(x_in, xbp0, xtp0);

  bf16* xbps[2] = {xbp0, xbp1};
  bf16* xtps[2] = {xtp0, xtp1};
  for (int l = 0; l < L_; ++l) {
    const int pi = l & 1, po = 1 - pi;
    gat_layer<<<dim3((N_ / 64) * B_), 512, 0, stream>>>(
        xbps[pi], xtps[pi], xbps[po], xtps[po],
        wb + l * DD2, battn + l * D_,
        wb + (4 + l) * DD2, b0 + l * D_,
        wb + (8 + l) * DD2, b1 + l * D_,
        adj, (l == 0) ? nullptr : bits, (l == 0) ? bits : nullptr,
        out_attn + (size_t)l * B_ * N_ * N_);
  }
  final_proj<<<dim3((B_ * N_) / 32), 256, 0, stream>>>(
      xbps[0], wb + 12 * DD2, bfin, out_x);
}